// Round 5
// baseline (221.110 us; speedup 1.0000x reference)
//
#include <hip/hip_runtime.h>
#include <hip/hip_cooperative_groups.h>

namespace cg = cooperative_groups;

#define HID 128
#define FEAT 16
#define N_PER 100000
#define NUM_ACTIONS 75000
#define N_NODES 100000
#define N_GRAPHS 512

// ws float layout:
// [0..143]   wg   = glob_W @ p   (globs part 0..127, feat part 128..143)
// [144..287] wn   = node_W @ p   (nodes part 144..271, feat part 272..287)
// [288..415] qe   = (e2_W @ p)[0:128]
// [416..687] w1   = e1_W @ qEE   (row 416..543, feat 544..559, col 560..687)
// [688] cg=glob_b.p  [689] cn=node_b.p  [690] ce=e1_b.qEE+e2_b.p  [691] pb
// [1024 ..]             nscal: float4 per node (x=.wr, y=.wc, z=.wn)
// [1024+4*N_NODES ..]   gscal: float per graph
#define NSCAL_OFF 1024
#define GSCAL_OFF (NSCAL_OFF + 4 * N_NODES)

__device__ __forceinline__ float dot4(float4 a, float4 b) {
    return a.x * b.x + a.y * b.y + a.z * b.z + a.w * b.w;
}

__global__ __launch_bounds__(256, 4) void fused_kernel(
    const float* __restrict__ globs, const float* __restrict__ nodes,
    const float* __restrict__ edges,
    const float* __restrict__ ag, const float* __restrict__ an,
    const float* __restrict__ ae,
    const float* __restrict__ glob_W, const float* __restrict__ glob_b,
    const float* __restrict__ node_W, const float* __restrict__ node_b,
    const float* __restrict__ e1_W,  const float* __restrict__ e1_b,
    const float* __restrict__ e2_W,  const float* __restrict__ e2_b,
    const float* __restrict__ pol_W, const float* __restrict__ pol_b,
    const int* __restrict__ row, const int* __restrict__ col,
    const int* __restrict__ U, const int* __restrict__ V,
    const int* __restrict__ E,
    float* __restrict__ ws, float* __restrict__ out)
{
    cg::grid_group grid = cg::this_grid();
    const int tid  = threadIdx.x;
    const int bid  = blockIdx.x;
    const int wave = tid >> 6;
    const int lane = tid & 63;

    __shared__ float qEE[HID];

    // ================= Phase 1: fold (distributed; ~1 dot per wave) ========
    {
        const float2 p2 = *(const float2*)&pol_W[2 * lane];
        // blocks whose dots need qEE build it redundantly in LDS
        const bool needq = (bid >= 104 && bid <= 172);
        if (needq) {
            for (int k = wave; k < HID; k += 4) {
                const float2 x = *(const float2*)&e2_W[(HID + k) * HID + 2 * lane];
                float acc = x.x * p2.x + x.y * p2.y;
                #pragma unroll
                for (int m = 32; m; m >>= 1) acc += __shfl_xor(acc, m);
                if (lane == 0) qEE[k] = acc;
            }
            __syncthreads();
        }
        const int d = bid * 4 + wave;
        if (d == 691) {
            if (lane == 0) ws[691] = pol_b[0];
        } else if (d < 692) {
            float acc;
            if (d < 144) {
                const float2 x = *(const float2*)&glob_W[d * HID + 2 * lane];
                acc = x.x * p2.x + x.y * p2.y;
            } else if (d < 288) {
                const float2 x = *(const float2*)&node_W[(d - 144) * HID + 2 * lane];
                acc = x.x * p2.x + x.y * p2.y;
            } else if (d < 416) {
                const float2 x = *(const float2*)&e2_W[(d - 288) * HID + 2 * lane];
                acc = x.x * p2.x + x.y * p2.y;
            } else if (d < 688) {
                const float2 q2 = *(const float2*)&qEE[2 * lane];
                const float2 x  = *(const float2*)&e1_W[(d - 416) * HID + 2 * lane];
                acc = x.x * q2.x + x.y * q2.y;
            } else if (d == 688) {
                const float2 x = *(const float2*)&glob_b[2 * lane];
                acc = x.x * p2.x + x.y * p2.y;
            } else if (d == 689) {
                const float2 x = *(const float2*)&node_b[2 * lane];
                acc = x.x * p2.x + x.y * p2.y;
            } else { // 690
                const float2 q2 = *(const float2*)&qEE[2 * lane];
                const float2 x1 = *(const float2*)&e1_b[2 * lane];
                const float2 x2 = *(const float2*)&e2_b[2 * lane];
                acc = x1.x * q2.x + x1.y * q2.y + x2.x * p2.x + x2.y * p2.y;
            }
            #pragma unroll
            for (int m = 32; m; m >>= 1) acc += __shfl_xor(acc, m);
            if (lane == 0) ws[d] = acc;
        }
    }
    grid.sync();

    // ================= Phase 2: gscal + nscal (streaming) ===================
    {
        const int s  = tid & 31;
        const int hw = bid * 8 + (tid >> 5);          // global half-wave id
        const int nhw = gridDim.x * 8;

        if (hw < N_GRAPHS) {
            const float4 wg4 = *(const float4*)&ws[4 * s];
            const float4 x   = *(const float4*)&globs[hw * HID + 4 * s];
            float a = dot4(x, wg4);
            #pragma unroll
            for (int m = 16; m; m >>= 1) a += __shfl_xor(a, m);
            if (s == 0) ws[GSCAL_OFF + hw] = a;
        }

        const float4 fr = *(const float4*)&ws[416 + 4 * s];
        const float4 fc = *(const float4*)&ws[560 + 4 * s];
        const float4 fn = *(const float4*)&ws[144 + 4 * s];
        for (int h = hw; h < N_NODES; h += nhw) {
            const float4 x = *(const float4*)&nodes[h * HID + 4 * s];
            float ar = dot4(x, fr), ac = dot4(x, fc), az = dot4(x, fn);
            #pragma unroll
            for (int m = 16; m; m >>= 1) {
                ar += __shfl_xor(ar, m);
                ac += __shfl_xor(ac, m);
                az += __shfl_xor(az, m);
            }
            if (s == 0) *(float4*)&ws[NSCAL_OFF + 4 * h] = make_float4(ar, ac, az, 0.f);
        }
    }
    grid.sync();

    // ================= Phase 3: actions (R3 structure, grid-strided) ========
    if (wave < 2) {
        const bool isg = (wave == 0);
        const int qtr = lane >> 4, ql = lane & 15;
        const float* feats = isg ? ag : an;
        const int* idx     = isg ? U : V;
        const float4 wf = *(const float4*)&ws[(isg ? 0 : 144) + HID + 4 * (ql & 3)];
        const float cb  = 4.f * ws[isg ? 688 : 689] + ws[691];
        const int obase = isg ? 0 : 25000;
        for (int b = bid; b < 6250; b += gridDim.x) {
            const int al = 4 * b + qtr;
            const int gl = 4 * al;
            float p = 0.f;
            if ((ql & 3) == 0) {
                const int id = idx[gl + (ql >> 2)];
                p = isg ? ws[GSCAL_OFF + id] : ws[NSCAL_OFF + 4 * id + 2];
            }
            const float4 f = *(const float4*)&feats[gl * FEAT + 4 * ql];
            p += dot4(f, wf);
            #pragma unroll
            for (int m = 8; m; m >>= 1) p += __shfl_xor(p, m);
            if (ql == 0) out[obase + al] = p + cb;
        }
    } else {
        const int s    = lane & 31;
        const int half = lane >> 5;
        const float4 we = *(const float4*)&ws[288 + 4 * s];
        const float4 wf = *(const float4*)&ws[544 + 4 * (s & 3)];
        const float cb  = 4.f * ws[690] + ws[691];
        for (int b = bid; b < 6250; b += gridDim.x) {
            const int j  = b + 6250 * (wave - 2);     // 0..12499
            const int al = 2 * j + half;              // 0..24999
            const int gl = 4 * al;
            const int4 e4 = *(const int4*)&E[gl];
            const int e[4] = { e4.x, e4.y, e4.z, e4.w };
            float p = 0.f;
            if (s < 8) {
                const int ei = e[s & 3];
                const int id = (s < 4) ? row[ei] : col[ei];
                p = ws[NSCAL_OFF + 4 * id + ((s < 4) ? 0 : 1)];
            }
            #pragma unroll
            for (int i = 0; i < 4; ++i) {
                const float4 x = *(const float4*)&edges[e[i] * HID + 4 * s];
                p += dot4(x, we);
            }
            if (s < 16) {
                const float4 f = *(const float4*)&ae[gl * FEAT + 4 * s];
                p += dot4(f, wf);
            }
            #pragma unroll
            for (int m = 16; m; m >>= 1) p += __shfl_xor(p, m);
            if (s == 0) out[50000 + al] = p + cb;
        }
    }
}

extern "C" void kernel_launch(void* const* d_in, const int* in_sizes, int n_in,
                              void* d_out, int out_size, void* d_ws, size_t ws_size,
                              hipStream_t stream)
{
    const float* globs  = (const float*)d_in[0];
    const float* nodes  = (const float*)d_in[1];
    const float* edges  = (const float*)d_in[2];
    const float* ag     = (const float*)d_in[3];
    const float* an     = (const float*)d_in[4];
    const float* ae     = (const float*)d_in[5];
    const float* glob_W = (const float*)d_in[6];
    const float* glob_b = (const float*)d_in[7];
    const float* node_W = (const float*)d_in[8];
    const float* node_b = (const float*)d_in[9];
    const float* e1_W   = (const float*)d_in[10];
    const float* e1_b   = (const float*)d_in[11];
    const float* e2_W   = (const float*)d_in[12];
    const float* e2_b   = (const float*)d_in[13];
    const float* pol_W  = (const float*)d_in[14];
    const float* pol_b  = (const float*)d_in[15];
    const int*   row    = (const int*)d_in[16];
    const int*   col    = (const int*)d_in[17];
    const int*   U      = (const int*)d_in[18];
    const int*   V      = (const int*)d_in[20];
    const int*   E      = (const int*)d_in[22];

    float* ws  = (float*)d_ws;
    float* out = (float*)d_out;

    // Deterministic occupancy-derived grid (pure host query; no alloc/sync).
    int occ = 0;
    if (hipOccupancyMaxActiveBlocksPerMultiprocessor(&occ, (const void*)fused_kernel,
                                                     256, 0) != hipSuccess || occ < 1)
        occ = 2;
    int nblk = 256 * occ;
    if (nblk > 1024) nblk = 1024;

    void* args[] = {
        (void*)&globs, (void*)&nodes, (void*)&edges,
        (void*)&ag, (void*)&an, (void*)&ae,
        (void*)&glob_W, (void*)&glob_b, (void*)&node_W, (void*)&node_b,
        (void*)&e1_W, (void*)&e1_b, (void*)&e2_W, (void*)&e2_b,
        (void*)&pol_W, (void*)&pol_b,
        (void*)&row, (void*)&col, (void*)&U, (void*)&V, (void*)&E,
        (void*)&ws, (void*)&out,
    };
    hipLaunchCooperativeKernel((const void*)fused_kernel, dim3(nblk), dim3(256),
                               args, 0, stream);
}

// Round 6
// 37.103 us; speedup vs baseline: 5.9593x; 5.9593x over previous
//
#include <hip/hip_runtime.h>

#define HID 128
#define FEAT 16
#define N_PER 100000
#define NUM_ACTIONS 75000
#define N_NODES 100000
#define N_GRAPHS 512

// ws float layout:
// [0..143]   wg   = glob_W @ p   (globs part 0..127, feat part 128..143)
// [144..287] wn   = node_W @ p   (nodes part 144..271, feat part 272..287)
// [288..415] qe   = (e2_W @ p)[0:128]
// [416..687] w1   = e1_W @ qEE   (row 416..543, feat 544..559, col 560..687)
// [688] cg=glob_b.p  [689] cn=node_b.p  [690] ce=e1_b.qEE+e2_b.p  [691] pb
// [1024 ..]             nscal: float4 per node (x=.wr, y=.wc, z=.wn)
// [1024+4*N_NODES ..]   gscal: float per graph
#define NSCAL_OFF 1024
#define GSCAL_OFF (NSCAL_OFF + 4 * N_NODES)

__device__ __forceinline__ float dot4(float4 a, float4 b) {
    return a.x * b.x + a.y * b.y + a.z * b.z + a.w * b.w;
}

// ---- DPP sum reductions (VALU-only, no LDS pipe) ----
template <int CTRL>
__device__ __forceinline__ float dpp_mov(float x) {
    return __int_as_float(__builtin_amdgcn_update_dpp(
        0, __float_as_int(x), CTRL, 0xF, 0xF, true));
}
// sum over 16-lane quarter; valid in lane 15 (mod 16)
__device__ __forceinline__ float red16(float x) {
    x += dpp_mov<0x111>(x);   // row_shr:1
    x += dpp_mov<0x112>(x);   // row_shr:2
    x += dpp_mov<0x114>(x);   // row_shr:4
    x += dpp_mov<0x118>(x);   // row_shr:8
    return x;
}
// sum over 32-lane half; valid in lane 31 (mod 32)
__device__ __forceinline__ float red32(float x) {
    x = red16(x);
    x += dpp_mov<0x142>(x);   // row_bcast:15
    return x;
}
// sum over full 64-lane wave; valid in lane 63
__device__ __forceinline__ float red64(float x) {
    x = red32(x);
    x += dpp_mov<0x143>(x);   // row_bcast:31
    return x;
}

// 44 blocks x 1024 threads. Blocks 26..43 build qEE[128] in LDS via 32
// half-waves (float4/lane, 4 rounds). Then each of the 704 waves does <=1
// of the 692 folded dots (float2/lane, 64-lane DPP reduce).
__global__ __launch_bounds__(1024) void fold_kernel(
    const float* __restrict__ glob_W, const float* __restrict__ glob_b,
    const float* __restrict__ node_W, const float* __restrict__ node_b,
    const float* __restrict__ e1_W,  const float* __restrict__ e1_b,
    const float* __restrict__ e2_W,  const float* __restrict__ e2_b,
    const float* __restrict__ pol_W, const float* __restrict__ pol_b,
    float* __restrict__ ws)
{
    __shared__ float qEE[HID];
    const int t = threadIdx.x, wave = t >> 6, lane = t & 63;
    const int bid = blockIdx.x;

    const bool needq = (bid >= 26 && bid <= 43);
    if (needq) {
        const int hw = t >> 5, s = t & 31;
        const float4 p4 = *(const float4*)&pol_W[4 * s];
        #pragma unroll
        for (int r = 0; r < 4; ++r) {
            const int k = hw + 32 * r;
            const float4 x = *(const float4*)&e2_W[(HID + k) * HID + 4 * s];
            float acc = red32(dot4(x, p4));
            if (s == 31) qEE[k] = acc;
        }
        __syncthreads();
    }

    const float2 p2 = *(const float2*)&pol_W[2 * lane];
    const int d = bid * 16 + wave;
    if (d == 691) {
        if (lane == 0) ws[691] = pol_b[0];
    } else if (d < 692) {
        float acc;
        if (d < 144) {
            const float2 x = *(const float2*)&glob_W[d * HID + 2 * lane];
            acc = x.x * p2.x + x.y * p2.y;
        } else if (d < 288) {
            const float2 x = *(const float2*)&node_W[(d - 144) * HID + 2 * lane];
            acc = x.x * p2.x + x.y * p2.y;
        } else if (d < 416) {
            const float2 x = *(const float2*)&e2_W[(d - 288) * HID + 2 * lane];
            acc = x.x * p2.x + x.y * p2.y;
        } else if (d < 688) {
            const float2 q2 = *(const float2*)&qEE[2 * lane];
            const float2 x  = *(const float2*)&e1_W[(d - 416) * HID + 2 * lane];
            acc = x.x * q2.x + x.y * q2.y;
        } else if (d == 688) {
            const float2 x = *(const float2*)&glob_b[2 * lane];
            acc = x.x * p2.x + x.y * p2.y;
        } else if (d == 689) {
            const float2 x = *(const float2*)&node_b[2 * lane];
            acc = x.x * p2.x + x.y * p2.y;
        } else { // 690
            const float2 q2 = *(const float2*)&qEE[2 * lane];
            const float2 x1 = *(const float2*)&e1_b[2 * lane];
            const float2 x2 = *(const float2*)&e2_b[2 * lane];
            acc = x1.x * q2.x + x1.y * q2.y + x2.x * p2.x + x2.y * p2.y;
        }
        acc = red64(acc);
        if (lane == 63) ws[d] = acc;
    }
}

// Streaming precompute: half-wave per node row (coalesced 512B reads),
// 3 dots (wr, wc, wn) -> nscal float4. Tail half-waves do gscal.
__global__ __launch_bounds__(256) void precompute_kernel(
    const float* __restrict__ nodes, const float* __restrict__ globs,
    float* __restrict__ ws)
{
    const int t = threadIdx.x, s = t & 31;
    const int h = blockIdx.x * 8 + (t >> 5);
    if (h < N_NODES) {
        const float4 fr = *(const float4*)&ws[416 + 4 * s];
        const float4 fc = *(const float4*)&ws[560 + 4 * s];
        const float4 fn = *(const float4*)&ws[144 + 4 * s];
        const float4 x  = *(const float4*)&nodes[h * HID + 4 * s];
        const float ar = red32(dot4(x, fr));
        const float ac = red32(dot4(x, fc));
        const float az = red32(dot4(x, fn));
        if (s == 31) *(float4*)&ws[NSCAL_OFF + 4 * h] = make_float4(ar, ac, az, 0.f);
    } else if (h < N_NODES + N_GRAPHS) {
        const int u = h - N_NODES;
        const float4 fg = *(const float4*)&ws[4 * s];
        const float4 x  = *(const float4*)&globs[u * HID + 4 * s];
        const float a = red32(dot4(x, fg));
        if (s == 31) ws[GSCAL_OFF + u] = a;
    }
}

// Each block: wave0 = glob (4 actions, 16 lanes each), wave1 = node,
// wave2+3 = edge (2 actions/wave, 32 lanes per action).
__global__ __launch_bounds__(256) void actions_kernel(
    const float* __restrict__ edges,
    const float* __restrict__ ag, const float* __restrict__ an,
    const float* __restrict__ ae,
    const int* __restrict__ row, const int* __restrict__ col,
    const int* __restrict__ U, const int* __restrict__ V,
    const int* __restrict__ E,
    const float* __restrict__ ws, float* __restrict__ out)
{
    const int b    = blockIdx.x;            // 0..6249
    const int wave = threadIdx.x >> 6;
    const int lane = threadIdx.x & 63;

    if (wave < 2) {
        const bool isg = (wave == 0);
        const int qtr = lane >> 4, ql = lane & 15;
        const int al  = 4 * b + qtr;          // branch-local action
        const int gl  = 4 * al;               // branch-local row base
        const float* feats = isg ? ag : an;
        const int* idx     = isg ? U : V;
        const int wbase    = isg ? 0 : 144;

        float p = 0.f;
        if ((ql & 3) == 0) {
            const int id = idx[gl + (ql >> 2)];
            p = isg ? ws[GSCAL_OFF + id] : ws[NSCAL_OFF + 4 * id + 2];
        }
        const float4 f  = *(const float4*)&feats[gl * FEAT + 4 * ql];
        const float4 wf = *(const float4*)&ws[wbase + HID + 4 * (ql & 3)];
        p = red16(p + dot4(f, wf));
        if (ql == 15)
            out[(isg ? 0 : 25000) + al] = p + 4.f * ws[isg ? 688 : 689] + ws[691];
    } else {
        const int j = b + 6250 * (wave - 2);  // 0..12499
        const int s = lane & 31;
        const int al = 2 * j + (lane >> 5);   // branch-local action 0..24999
        const int gl = 4 * al;                // branch-local row base

        // dependent gather chain first: E -> row/col -> nscal
        const int4 e4 = *(const int4*)&E[gl];
        const int e[4] = { e4.x, e4.y, e4.z, e4.w };
        float p = 0.f;
        if (s < 8) {
            const int ei = e[s & 3];
            const int id = (s < 4) ? row[ei] : col[ei];
            p = ws[NSCAL_OFF + 4 * id + ((s < 4) ? 0 : 1)];
        }

        const float4 we = *(const float4*)&ws[288 + 4 * s];
        #pragma unroll
        for (int i = 0; i < 4; ++i) {
            const float4 x = *(const float4*)&edges[e[i] * HID + 4 * s];
            p += dot4(x, we);
        }
        if (s < 16) {
            const float4 f  = *(const float4*)&ae[gl * FEAT + 4 * s];
            const float4 wf = *(const float4*)&ws[544 + 4 * (s & 3)];
            p += dot4(f, wf);
        }
        p = red32(p);
        if (s == 31) out[50000 + al] = p + 4.f * ws[690] + ws[691];
    }
}

extern "C" void kernel_launch(void* const* d_in, const int* in_sizes, int n_in,
                              void* d_out, int out_size, void* d_ws, size_t ws_size,
                              hipStream_t stream)
{
    const float* globs  = (const float*)d_in[0];
    const float* nodes  = (const float*)d_in[1];
    const float* edges  = (const float*)d_in[2];
    const float* ag     = (const float*)d_in[3];
    const float* an     = (const float*)d_in[4];
    const float* ae     = (const float*)d_in[5];
    const float* glob_W = (const float*)d_in[6];
    const float* glob_b = (const float*)d_in[7];
    const float* node_W = (const float*)d_in[8];
    const float* node_b = (const float*)d_in[9];
    const float* e1_W   = (const float*)d_in[10];
    const float* e1_b   = (const float*)d_in[11];
    const float* e2_W   = (const float*)d_in[12];
    const float* e2_b   = (const float*)d_in[13];
    const float* pol_W  = (const float*)d_in[14];
    const float* pol_b  = (const float*)d_in[15];
    const int*   row    = (const int*)d_in[16];
    const int*   col    = (const int*)d_in[17];
    const int*   U      = (const int*)d_in[18];
    const int*   V      = (const int*)d_in[20];
    const int*   E      = (const int*)d_in[22];

    float* ws  = (float*)d_ws;
    float* out = (float*)d_out;

    hipLaunchKernelGGL(fold_kernel, dim3(44), dim3(1024), 0, stream,
                       glob_W, glob_b, node_W, node_b, e1_W, e1_b, e2_W, e2_b,
                       pol_W, pol_b, ws);
    hipLaunchKernelGGL(precompute_kernel, dim3((N_NODES + N_GRAPHS + 7) / 8), dim3(256),
                       0, stream, nodes, globs, ws);
    hipLaunchKernelGGL(actions_kernel, dim3(6250), dim3(256), 0, stream,
                       edges, ag, an, ae, row, col, U, V, E, ws, out);
}